// Round 1
// baseline (1097.684 us; speedup 1.0000x reference)
//
#include <hip/hip_runtime.h>
#include <math.h>

// Problem constants (compile-time, from reference)
#define N1v    4000
#define N2v    4000
#define G_DIMv 8000
#define R_DIMv 20000
#define M1v    1200
#define M2v    1200
#define MGv    2400
#define MRv    6000

// ws float layout: [0]=sum1 [1]=sum2 [2]=sum3 [3]=normPg^2 [4]=normPr^2
#define ACC_N 8

// main-kernel grid layout
#define CH   60                 // rows per i-chunk
#define JB1  10                 // ceil(2400/256)
#define JB23 24                 // ceil(6000/256)
#define IC1  20                 // 1200/60
#define IC2  20                 // 1200/60
#define IC3  40                 // 2400/60
#define S1_BLOCKS (JB1*IC1)     // 200
#define S2_BLOCKS (JB23*IC2)    // 480
#define S3_BLOCKS (JB23*IC3)    // 960
#define TOTAL_BLOCKS (S1_BLOCKS + S2_BLOCKS + S3_BLOCKS)  // 1640

__device__ __forceinline__ void softmax3(float a, float b, float c,
                                         float& p0, float& p1, float& p2) {
    float m = fmaxf(a, fmaxf(b, c));
    float e0 = expf(a - m), e1 = expf(b - m), e2 = expf(c - m);
    float inv = 1.0f / (e0 + e1 + e2);
    p0 = e0 * inv; p1 = e1 * inv; p2 = e2 * inv;
}

// Norms of Pg = softmax(C_g[mask_g]) and Pr = softmax(C_r[mask_r]) (Frobenius^2)
__global__ void norm_kernel(const float* __restrict__ Cg, const float* __restrict__ Cr,
                            const int* __restrict__ mg, const int* __restrict__ mr,
                            float* __restrict__ ws) {
    int idx = blockIdx.x * 256 + threadIdx.x;
    float vg = 0.0f, vr = 0.0f;
    if (idx < MGv) {
        int r = mg[idx];
        float p0, p1, p2;
        softmax3(Cg[r*3], Cg[r*3+1], Cg[r*3+2], p0, p1, p2);
        vg = p0*p0 + p1*p1 + p2*p2;
    } else if (idx < MGv + MRv) {
        int i = idx - MGv;
        int r = mr[i];
        float p0, p1, p2;
        softmax3(Cr[r*3], Cr[r*3+1], Cr[r*3+2], p0, p1, p2);
        vr = p0*p0 + p1*p1 + p2*p2;
    }
    #pragma unroll
    for (int o = 32; o > 0; o >>= 1) {
        vg += __shfl_down(vg, o, 64);
        vr += __shfl_down(vr, o, 64);
    }
    __shared__ float sA[4], sB[4];
    int lane = threadIdx.x & 63, w = threadIdx.x >> 6;
    if (lane == 0) { sA[w] = vg; sB[w] = vr; }
    __syncthreads();
    if (threadIdx.x == 0) {
        atomicAdd(&ws[3], sA[0] + sA[1] + sA[2] + sA[3]);
        atomicAdd(&ws[4], sB[0] + sB[1] + sB[2] + sB[3]);
    }
}

// Fused: loss1 (G residual), loss2 (R residual), loss3 (A * PgPr^T trace sum)
__global__ __launch_bounds__(256) void main_kernel(
    const float* __restrict__ G, const float* __restrict__ R, const float* __restrict__ A,
    const float* __restrict__ C1, const float* __restrict__ C2,
    const float* __restrict__ Cg, const float* __restrict__ Cr,
    const float* __restrict__ Ai,
    const float* __restrict__ bg, const float* __restrict__ br,
    const float* __restrict__ b1, const float* __restrict__ b2,
    const int* __restrict__ m1, const int* __restrict__ m2,
    const int* __restrict__ mg, const int* __restrict__ mr,
    float* __restrict__ ws) {
    __shared__ int   s_row[CH];
    __shared__ float s_vec[CH * 3];
    __shared__ float s_bias[CH];
    __shared__ float s_red[4];

    int bid = blockIdx.x;
    int sec, jb, chunk;
    if (bid < S1_BLOCKS)                  { sec = 0; jb = bid % JB1;  chunk = bid / JB1; }
    else if (bid < S1_BLOCKS + S2_BLOCKS) { int b = bid - S1_BLOCKS;  sec = 1; jb = b % JB23; chunk = b / JB23; }
    else                                  { int b = bid - S1_BLOCKS - S2_BLOCKS; sec = 2; jb = b % JB23; chunk = b / JB23; }

    const int *rmask, *cmask;
    const float *rsrc, *csrc, *data, *biasr, *biasc;
    int NIs, NJs; long stride;
    if (sec == 0) {
        rmask = m1; cmask = mg; rsrc = C1; csrc = Cg; data = G;
        biasr = b1; biasc = bg; NIs = M1v; NJs = MGv; stride = G_DIMv;
    } else if (sec == 1) {
        rmask = m2; cmask = mr; rsrc = C2; csrc = Cr; data = R;
        biasr = b2; biasc = br; NIs = M2v; NJs = MRv; stride = R_DIMv;
    } else {
        rmask = mg; cmask = mr; rsrc = Cg; csrc = Cr; data = A;
        biasr = nullptr; biasc = nullptr; NIs = MGv; NJs = MRv; stride = R_DIMv;
    }

    int tid = threadIdx.x;
    int j = jb * 256 + tid;
    bool jvalid = j < NJs;

    // per-lane column state (registers)
    int cj = 0; float v0 = 0, v1 = 0, v2 = 0, bc = 0;
    if (jvalid) {
        cj = cmask[j];
        softmax3(csrc[cj*3], csrc[cj*3+1], csrc[cj*3+2], v0, v1, v2);
        if (biasc) bc = biasc[cj];
    }

    // stage row chunk into LDS (softmax + optional @Ai + bias gather)
    int i0 = chunk * CH;
    for (int t = tid; t < CH; t += 256) {
        int ii = i0 + t;
        if (ii < NIs) {
            int r = rmask[ii];
            float p0, p1, p2;
            softmax3(rsrc[r*3], rsrc[r*3+1], rsrc[r*3+2], p0, p1, p2);
            float w0, w1, w2;
            if (sec == 2) { w0 = p0; w1 = p1; w2 = p2; }
            else {
                w0 = p0*Ai[0] + p1*Ai[3] + p2*Ai[6];
                w1 = p0*Ai[1] + p1*Ai[4] + p2*Ai[7];
                w2 = p0*Ai[2] + p1*Ai[5] + p2*Ai[8];
            }
            s_row[t] = r;
            s_vec[t*3]   = w0;
            s_vec[t*3+1] = w1;
            s_vec[t*3+2] = w2;
            s_bias[t] = biasr ? biasr[r] : 0.0f;
        } else {
            s_row[t] = 0;
            s_vec[t*3] = s_vec[t*3+1] = s_vec[t*3+2] = 0.0f;
            s_bias[t] = 0.0f;
        }
    }
    __syncthreads();

    float acc = 0.0f;
    int nmax = NIs - i0; if (nmax > CH) nmax = CH;
    if (jvalid) {
        if (sec == 2) {
            for (int t = 0; t < nmax; t++) {
                long row = s_row[t];
                float x = data[row * stride + cj];
                float dot = s_vec[t*3]*v0 + s_vec[t*3+1]*v1 + s_vec[t*3+2]*v2;
                acc += x * dot;
            }
        } else {
            for (int t = 0; t < nmax; t++) {
                long row = s_row[t];
                float x = data[row * stride + cj];
                float pred = s_vec[t*3]*v0 + s_vec[t*3+1]*v1 + s_vec[t*3+2]*v2;
                float d = x - pred - bc - s_bias[t];
                acc += d * d;
            }
        }
    }

    #pragma unroll
    for (int o = 32; o > 0; o >>= 1) acc += __shfl_down(acc, o, 64);
    int lane = tid & 63, w = tid >> 6;
    if (lane == 0) s_red[w] = acc;
    __syncthreads();
    if (tid == 0) {
        float tot = s_red[0] + s_red[1] + s_red[2] + s_red[3];
        atomicAdd(&ws[sec], tot);
    }
}

__global__ void finalize_kernel(const float* __restrict__ ws, float* __restrict__ out) {
    if (threadIdx.x == 0 && blockIdx.x == 0) {
        float l1 = ws[0] * (1.0f / (float)(M1v * MGv)) * 1000.0f;  // ALPHA0*loss1
        float l2 = ws[1] * (1.0f / (float)(M2v * MRv)) * 1000.0f;  // ALPHA1*loss2
        float l3 = -ws[2] / sqrtf(ws[3] * ws[4]) * 100.0f;          // ALPHA2*loss3
        out[0] = l1 + l2 + l3;   // ALPHA3 = 0 -> loss4 contributes exactly 0
        out[1] = l1;
        out[2] = l2;
        out[3] = l3;
        out[4] = 0.0f;
    }
}

extern "C" void kernel_launch(void* const* d_in, const int* in_sizes, int n_in,
                              void* d_out, int out_size, void* d_ws, size_t ws_size,
                              hipStream_t stream) {
    const float* G  = (const float*)d_in[0];
    const float* R  = (const float*)d_in[1];
    const float* A  = (const float*)d_in[2];
    const float* C1 = (const float*)d_in[3];
    const float* C2 = (const float*)d_in[4];
    const float* Cg = (const float*)d_in[5];
    const float* Cr = (const float*)d_in[6];
    const float* Ai = (const float*)d_in[7];
    const float* bg = (const float*)d_in[8];
    const float* br = (const float*)d_in[9];
    const float* b1 = (const float*)d_in[10];
    const float* b2 = (const float*)d_in[11];
    const int* m1 = (const int*)d_in[12];
    const int* m2 = (const int*)d_in[13];
    const int* mg = (const int*)d_in[14];
    const int* mr = (const int*)d_in[15];
    float* ws  = (float*)d_ws;
    float* out = (float*)d_out;

    hipMemsetAsync(d_ws, 0, ACC_N * sizeof(float), stream);
    norm_kernel<<<(MGv + MRv + 255) / 256, 256, 0, stream>>>(Cg, Cr, mg, mr, ws);
    main_kernel<<<TOTAL_BLOCKS, 256, 0, stream>>>(G, R, A, C1, C2, Cg, Cr, Ai,
                                                  bg, br, b1, b2, m1, m2, mg, mr, ws);
    finalize_kernel<<<1, 64, 0, stream>>>(ws, out);
}

// Round 2
// 948.328 us; speedup vs baseline: 1.1575x; 1.1575x over previous
//
#include <hip/hip_runtime.h>
#include <math.h>

// Problem constants (from reference)
#define N1v 4000
#define N2v 4000
#define GDv 8000
#define RDv 20000
#define M1v 1200
#define M2v 1200
#define MGv 2400
#define MRv 6000

// ---- ws layout (offsets in 4-byte units; float4 arrays 16B-aligned) ----
#define W_ACC    0                  // [0]=s1 [1]=s2 [2]=s3 [3]=||Pg||^2 [4]=||Pr||^2
#define W_NC     8                  // int[4]: n1u, n2u, n3u
#define W_CNT1   16
#define W_CNT2   (W_CNT1 + N1v)     // 4016
#define W_CNTG   (W_CNT2 + N2v)     // 8016
#define W_CNTR   (W_CNTG + GDv)     // 16016
#define W_ZEND   (W_CNTR + RDv)     // 36016  (memset zeroes [0, W_ZEND))
#define W_COLG4  W_ZEND             // float4[GDv]: {s*p0,s*p1,s*p2,s}, s=sqrt(cnt)
#define W_COLGB  (W_COLG4 + 4*GDv)  // float[GDv]: s*bg[c]
#define W_COLR24 (W_COLGB + GDv)    // float4[RDv]: {s*p0,s*p1,s*p2,s}
#define W_COLR2B (W_COLR24 + 4*RDv) // float[RDv]: s*br[c]
#define W_COLR34 (W_COLR2B + RDv)   // float4[RDv]: {n*p0,n*p1,n*p2,0}
#define W_R1ID   (W_COLR34 + 4*RDv) // int[M1v]
#define W_R14    (W_R1ID + M1v)     // float4[M1v]: {W0,W1,W2,b1[r]}
#define W_R1C    (W_R14 + 4*M1v)    // float[M1v]: cnt
#define W_R2ID   (W_R1C + M1v)
#define W_R24    (W_R2ID + M2v)
#define W_R2C    (W_R24 + 4*M2v)
#define W_R3ID   (W_R2C + M2v)      // int[MGv]
#define W_R34    (W_R3ID + MGv)     // float4[MGv]: {Pg0,Pg1,Pg2,0}
#define W_R3C    (W_R34 + 4*MGv)    // float[MGv]: cnt_g

// ---- main kernel tiling ----
#define RC  32                      // rows per chunk
#define CT  2048                    // columns per tile (8 cols/thread as 2 float4)
#define T1  4                       // ceil(8000/2048)
#define T23 10                      // ceil(20000/2048)
#define CH12 38                     // ceil(1200/32)  (worst-case unique rows)
#define CH3  75                     // ceil(2400/32)
#define S1B (T1*CH12)               // 152
#define S2B (T23*CH12)              // 380
#define S3B (T23*CH3)               // 750
#define TOTB (S1B + S2B + S3B)      // 1282

__device__ __forceinline__ void softmax3(float a, float b, float c,
                                         float& p0, float& p1, float& p2) {
    float m = fmaxf(a, fmaxf(b, c));
    float e0 = expf(a - m), e1 = expf(b - m), e2 = expf(c - m);
    float inv = 1.0f / (e0 + e1 + e2);
    p0 = e0 * inv; p1 = e1 * inv; p2 = e2 * inv;
}

// 1) Histogram the four masks into count arrays
__global__ void hist_kernel(const int* __restrict__ m1, const int* __restrict__ m2,
                            const int* __restrict__ mg, const int* __restrict__ mr,
                            float* __restrict__ ws) {
    int idx = blockIdx.x * 256 + threadIdx.x;
    int* cnt1 = (int*)(ws + W_CNT1);
    int* cnt2 = (int*)(ws + W_CNT2);
    int* cntg = (int*)(ws + W_CNTG);
    int* cntr = (int*)(ws + W_CNTR);
    if (idx < M1v)                          atomicAdd(&cnt1[m1[idx]], 1);
    else if (idx < M1v + M2v)               atomicAdd(&cnt2[m2[idx - M1v]], 1);
    else if (idx < M1v + M2v + MGv)         atomicAdd(&cntg[mg[idx - M1v - M2v]], 1);
    else if (idx < M1v + M2v + MGv + MRv)   atomicAdd(&cntr[mr[idx - M1v - M2v - MGv]], 1);
}

// 2) Dense column state over all G_DIM + R_DIM columns; also accumulates norms
__global__ void colstate_kernel(const float* __restrict__ Cg, const float* __restrict__ Cr,
                                const float* __restrict__ bg, const float* __restrict__ br,
                                float* __restrict__ ws) {
    int idx = blockIdx.x * 256 + threadIdx.x;
    const int* cntg = (const int*)(ws + W_CNTG);
    const int* cntr = (const int*)(ws + W_CNTR);
    float vg = 0.0f, vr = 0.0f;
    if (idx < GDv) {
        int c = idx;
        float n = (float)cntg[c];
        float p0, p1, p2;
        softmax3(Cg[c*3], Cg[c*3+1], Cg[c*3+2], p0, p1, p2);
        float s = sqrtf(n);
        ((float4*)(ws + W_COLG4))[c] = make_float4(s*p0, s*p1, s*p2, s);
        ws[W_COLGB + c] = s * bg[c];
        vg = n * (p0*p0 + p1*p1 + p2*p2);
    } else if (idx < GDv + RDv) {
        int c = idx - GDv;
        float n = (float)cntr[c];
        float p0, p1, p2;
        softmax3(Cr[c*3], Cr[c*3+1], Cr[c*3+2], p0, p1, p2);
        float s = sqrtf(n);
        ((float4*)(ws + W_COLR24))[c] = make_float4(s*p0, s*p1, s*p2, s);
        ws[W_COLR2B + c] = s * br[c];
        ((float4*)(ws + W_COLR34))[c] = make_float4(n*p0, n*p1, n*p2, 0.0f);
        vr = n * (p0*p0 + p1*p1 + p2*p2);
    }
    #pragma unroll
    for (int o = 32; o > 0; o >>= 1) {
        vg += __shfl_down(vg, o, 64);
        vr += __shfl_down(vr, o, 64);
    }
    __shared__ float sA[4], sB[4];
    int lane = threadIdx.x & 63, w = threadIdx.x >> 6;
    if (lane == 0) { sA[w] = vg; sB[w] = vr; }
    __syncthreads();
    if (threadIdx.x == 0) {
        atomicAdd(&ws[3], sA[0] + sA[1] + sA[2] + sA[3]);
        atomicAdd(&ws[4], sB[0] + sB[1] + sB[2] + sB[3]);
    }
}

// 3) Compact unique rows (order-irrelevant) with per-row state
__global__ void rowcompact_kernel(const float* __restrict__ C1, const float* __restrict__ C2,
                                  const float* __restrict__ Cg, const float* __restrict__ Ai,
                                  const float* __restrict__ b1, const float* __restrict__ b2,
                                  float* __restrict__ ws) {
    int idx = blockIdx.x * 256 + threadIdx.x;
    int* nc = (int*)(ws + W_NC);
    if (idx < N1v) {
        int r = idx;
        int c = ((const int*)(ws + W_CNT1))[r];
        if (c > 0) {
            int k = atomicAdd(&nc[0], 1);
            float p0, p1, p2;
            softmax3(C1[r*3], C1[r*3+1], C1[r*3+2], p0, p1, p2);
            float w0 = p0*Ai[0] + p1*Ai[3] + p2*Ai[6];
            float w1 = p0*Ai[1] + p1*Ai[4] + p2*Ai[7];
            float w2 = p0*Ai[2] + p1*Ai[5] + p2*Ai[8];
            ((int*)(ws + W_R1ID))[k] = r;
            ((float4*)(ws + W_R14))[k] = make_float4(w0, w1, w2, b1[r]);
            ws[W_R1C + k] = (float)c;
        }
    } else if (idx < N1v + N2v) {
        int r = idx - N1v;
        int c = ((const int*)(ws + W_CNT2))[r];
        if (c > 0) {
            int k = atomicAdd(&nc[1], 1);
            float p0, p1, p2;
            softmax3(C2[r*3], C2[r*3+1], C2[r*3+2], p0, p1, p2);
            float w0 = p0*Ai[0] + p1*Ai[3] + p2*Ai[6];
            float w1 = p0*Ai[1] + p1*Ai[4] + p2*Ai[7];
            float w2 = p0*Ai[2] + p1*Ai[5] + p2*Ai[8];
            ((int*)(ws + W_R2ID))[k] = r;
            ((float4*)(ws + W_R24))[k] = make_float4(w0, w1, w2, b2[r]);
            ws[W_R2C + k] = (float)c;
        }
    } else if (idx < N1v + N2v + GDv) {
        int g = idx - N1v - N2v;
        int c = ((const int*)(ws + W_CNTG))[g];
        if (c > 0) {
            int k = atomicAdd(&nc[2], 1);
            float p0, p1, p2;
            softmax3(Cg[g*3], Cg[g*3+1], Cg[g*3+2], p0, p1, p2);
            ((int*)(ws + W_R3ID))[k] = g;
            ((float4*)(ws + W_R34))[k] = make_float4(p0, p1, p2, 0.0f);
            ws[W_R3C + k] = (float)c;
        }
    }
}

// 4) Dense, coalesced main sweep: compacted rows x all columns
__global__ __launch_bounds__(256) void main_kernel(
    const float* __restrict__ G, const float* __restrict__ R, const float* __restrict__ A,
    float* __restrict__ ws) {
    int bid = blockIdx.x;
    int sec, tile, chunk;
    if (bid < S1B)            { sec = 0; tile = bid / CH12; chunk = bid % CH12; }
    else if (bid < S1B + S2B) { int b = bid - S1B; sec = 1; tile = b / CH12; chunk = b % CH12; }
    else                      { int b = bid - S1B - S2B; sec = 2; tile = b / CH3; chunk = b % CH3; }

    const float *data; const float4 *cst; const float *cbias;
    const int *rid; const float4 *rst; const float *rcn;
    int NC; long stride; int nidx;
    if (sec == 0) {
        data = G; stride = GDv; NC = GDv;
        cst = (const float4*)(ws + W_COLG4); cbias = ws + W_COLGB;
        rid = (const int*)(ws + W_R1ID); rst = (const float4*)(ws + W_R14); rcn = ws + W_R1C;
        nidx = 0;
    } else if (sec == 1) {
        data = R; stride = RDv; NC = RDv;
        cst = (const float4*)(ws + W_COLR24); cbias = ws + W_COLR2B;
        rid = (const int*)(ws + W_R2ID); rst = (const float4*)(ws + W_R24); rcn = ws + W_R2C;
        nidx = 1;
    } else {
        data = A; stride = RDv; NC = RDv;
        cst = (const float4*)(ws + W_COLR34); cbias = nullptr;
        rid = (const int*)(ws + W_R3ID); rst = (const float4*)(ws + W_R34); rcn = ws + W_R3C;
        nidx = 2;
    }

    int n = ((const int*)(ws + W_NC))[nidx];
    int r0 = chunk * RC;
    if (r0 >= n) return;
    int nr = min(n - r0, RC);

    __shared__ int   s_rid[RC];
    __shared__ float4 s_rw[RC];
    __shared__ float s_rc[RC];
    __shared__ float s_red[4];
    int tid = threadIdx.x;
    if (tid < RC && tid < nr) {
        s_rid[tid] = rid[r0 + tid];
        s_rw[tid]  = rst[r0 + tid];
        s_rc[tid]  = rcn[r0 + tid];
    }
    __syncthreads();

    // Per-thread columns: two groups of 4 consecutive columns
    int cc0 = tile * CT + 4 * tid;
    int cc1 = cc0 + 1024;
    bool v0 = (cc0 < NC);
    bool v1 = (cc1 < NC);

    float4 ca[8];
    float  cb[8];
    #pragma unroll
    for (int q = 0; q < 8; q++) { ca[q] = make_float4(0,0,0,0); cb[q] = 0.0f; }
    if (v0) {
        #pragma unroll
        for (int q = 0; q < 4; q++) ca[q] = cst[cc0 + q];
        if (sec < 2) {
            #pragma unroll
            for (int q = 0; q < 4; q++) cb[q] = cbias[cc0 + q];
        }
    }
    if (v1) {
        #pragma unroll
        for (int q = 0; q < 4; q++) ca[4+q] = cst[cc1 + q];
        if (sec < 2) {
            #pragma unroll
            for (int q = 0; q < 4; q++) cb[4+q] = cbias[cc1 + q];
        }
    }

    float acc = 0.0f;
    for (int ir = 0; ir < nr; ir++) {
        long rrow = s_rid[ir];
        float4 rw = s_rw[ir];
        float  rc = s_rc[ir];
        const float* drow = data + rrow * stride;
        float4 x0 = v0 ? *(const float4*)(drow + cc0) : make_float4(0,0,0,0);
        float4 x1 = v1 ? *(const float4*)(drow + cc1) : make_float4(0,0,0,0);
        float xs[8] = {x0.x, x0.y, x0.z, x0.w, x1.x, x1.y, x1.z, x1.w};
        float racc = 0.0f;
        if (sec < 2) {
            #pragma unroll
            for (int q = 0; q < 8; q++) {
                // s*(x - pred - bias_c - b_r) with s,p' folded: see colstate
                float rp = ca[q].w * (xs[q] - rw.w)
                         - (rw.x*ca[q].x + rw.y*ca[q].y + rw.z*ca[q].z)
                         - cb[q];
                racc = fmaf(rp, rp, racc);
            }
        } else {
            #pragma unroll
            for (int q = 0; q < 8; q++) {
                float d = rw.x*ca[q].x + rw.y*ca[q].y + rw.z*ca[q].z;
                racc = fmaf(xs[q], d, racc);
            }
        }
        acc = fmaf(rc, racc, acc);
    }

    #pragma unroll
    for (int o = 32; o > 0; o >>= 1) acc += __shfl_down(acc, o, 64);
    int lane = tid & 63, w = tid >> 6;
    if (lane == 0) s_red[w] = acc;
    __syncthreads();
    if (tid == 0) atomicAdd(&ws[nidx], s_red[0] + s_red[1] + s_red[2] + s_red[3]);
}

__global__ void finalize_kernel(const float* __restrict__ ws, float* __restrict__ out) {
    if (threadIdx.x == 0 && blockIdx.x == 0) {
        float l1 = ws[0] * (1.0f / (float)(M1v * MGv)) * 1000.0f;
        float l2 = ws[1] * (1.0f / (float)(M2v * MRv)) * 1000.0f;
        float l3 = -ws[2] / sqrtf(ws[3] * ws[4]) * 100.0f;
        out[0] = l1 + l2 + l3;   // ALPHA3 = 0 -> loss4 contributes exactly 0
        out[1] = l1;
        out[2] = l2;
        out[3] = l3;
        out[4] = 0.0f;
    }
}

extern "C" void kernel_launch(void* const* d_in, const int* in_sizes, int n_in,
                              void* d_out, int out_size, void* d_ws, size_t ws_size,
                              hipStream_t stream) {
    const float* G  = (const float*)d_in[0];
    const float* R  = (const float*)d_in[1];
    const float* A  = (const float*)d_in[2];
    const float* C1 = (const float*)d_in[3];
    const float* C2 = (const float*)d_in[4];
    const float* Cg = (const float*)d_in[5];
    const float* Cr = (const float*)d_in[6];
    const float* Ai = (const float*)d_in[7];
    const float* bg = (const float*)d_in[8];
    const float* br = (const float*)d_in[9];
    const float* b1 = (const float*)d_in[10];
    const float* b2 = (const float*)d_in[11];
    const int* m1 = (const int*)d_in[12];
    const int* m2 = (const int*)d_in[13];
    const int* mg = (const int*)d_in[14];
    const int* mr = (const int*)d_in[15];
    float* ws  = (float*)d_ws;
    float* out = (float*)d_out;

    hipMemsetAsync(d_ws, 0, (size_t)W_ZEND * 4, stream);
    hist_kernel<<<(M1v + M2v + MGv + MRv + 255) / 256, 256, 0, stream>>>(m1, m2, mg, mr, ws);
    colstate_kernel<<<(GDv + RDv + 255) / 256, 256, 0, stream>>>(Cg, Cr, bg, br, ws);
    rowcompact_kernel<<<(N1v + N2v + GDv + 255) / 256, 256, 0, stream>>>(C1, C2, Cg, Ai, b1, b2, ws);
    main_kernel<<<TOTB, 256, 0, stream>>>(G, R, A, ws);
    finalize_kernel<<<1, 64, 0, stream>>>(ws, out);
}